// Round 1
// baseline (1703.334 us; speedup 1.0000x reference)
//
#include <hip/hip_runtime.h>

#define T_ 512
#define B_ 64
#define H_ 512
#define LMAX 28
#define NROWS (T_*B_)   // 32768

typedef _Float16 f16;
typedef __attribute__((ext_vector_type(8))) _Float16 f16x8;
typedef __attribute__((ext_vector_type(4))) float fx4;

#define M_CNT 0
#define M_OFF 32
#define M_CUR 64

__device__ __forceinline__ float sigm(float z)  { return 1.0f / (1.0f + __expf(-z)); }
__device__ __forceinline__ float tanha(float z) { return 2.0f / (1.0f + __expf(-2.0f * z)) - 1.0f; }

// ---------------------------------------------------------------------------
// K0: pack [Wi;Wh] (fp32, (1024 rows k2) x (2048 cols)) into W2t fp16 [col][k2]
// ---------------------------------------------------------------------------
__global__ __launch_bounds__(256) void k_prepw(const float* __restrict__ Wi,
                                               const float* __restrict__ Wh,
                                               f16* __restrict__ W2t) {
    __shared__ float tile[64][65];
    const int c0  = blockIdx.x * 64;   // col tile
    const int k20 = blockIdx.y * 64;   // k2 tile
    const int tid = threadIdx.x;
    #pragma unroll
    for (int s = 0; s < 16; s++) {
        int k2r = s * 4 + (tid >> 6);
        int c   = tid & 63;
        int k2  = k20 + k2r;
        float v = (k2 < H_) ? Wi[(size_t)k2 * 2048 + c0 + c]
                            : Wh[(size_t)(k2 - H_) * 2048 + c0 + c];
        tile[c][k2r] = v;
    }
    __syncthreads();
    const int c  = tid >> 2;
    const int ch = tid & 3;
    f16 tmp[16];
    #pragma unroll
    for (int u = 0; u < 16; u++) tmp[u] = (f16)tile[c][ch * 16 + u];
    f16* dst = W2t + (size_t)(c0 + c) * 1024 + k20 + ch * 16;
    *(uint4*)(dst)     = *(const uint4*)(tmp);
    *(uint4*)(dst + 8) = *(const uint4*)(tmp + 8);
}

// ---------------------------------------------------------------------------
// K1: per-batch scan of resets -> level(t,b); counts per level; prefix offsets
// ---------------------------------------------------------------------------
__global__ void k_scan(const int* __restrict__ resets, int* __restrict__ lvl,
                       int* __restrict__ meta) {
    const int tid = threadIdx.x; // 64
    for (int i = tid; i < 96; i += 64) meta[i] = 0;
    __syncthreads();
    const int b = tid;
    int prev = 0;
    for (int t = 0; t < T_; t++) {
        int lv = (t == 0) ? 0 : (resets[t * B_ + b] ? 0 : prev + 1);
        lvl[t * B_ + b] = lv;
        int kk = lv < LMAX ? lv : LMAX;
        atomicAdd(&meta[M_CNT + kk], 1);
        prev = lv;
    }
    __syncthreads();
    if (tid == 0) {
        int acc = 0;
        for (int k = 0; k <= LMAX; k++) { meta[M_OFF + k] = acc; acc += meta[M_CNT + k]; }
    }
}

// ---------------------------------------------------------------------------
// K2: assign each (t,b) a row slot in its level's bucket
// ---------------------------------------------------------------------------
__global__ __launch_bounds__(256) void k_build(const int* __restrict__ lvl,
                                               int* __restrict__ meta,
                                               int* __restrict__ rowid,
                                               int* __restrict__ rmap) {
    int tb = blockIdx.x * 256 + threadIdx.x;
    if (tb >= NROWS) return;
    int lv = lvl[tb];
    int kk = lv < LMAX ? lv : LMAX;
    int pos = atomicAdd(&meta[M_CUR + kk], 1);
    int r = meta[M_OFF + kk] + pos;
    rowid[tb] = r;
    rmap[r] = tb;
}

// ---------------------------------------------------------------------------
// K3: gather x rows (fp32 -> fp16) into A[:, 0:512]
// ---------------------------------------------------------------------------
__global__ __launch_bounds__(256) void k_fillx(const float* __restrict__ xs,
                                               const int* __restrict__ rmap,
                                               f16* __restrict__ A) {
    int gid = blockIdx.x * 256 + threadIdx.x;  // NROWS*64 threads
    int r = gid >> 6, seg = gid & 63;
    int tb = rmap[r];
    const float4* src = (const float4*)(xs + (size_t)tb * H_ + seg * 8);
    float4 a = src[0];
    float4 c = src[1];
    f16x8 o;
    o[0]=(f16)a.x; o[1]=(f16)a.y; o[2]=(f16)a.z; o[3]=(f16)a.w;
    o[4]=(f16)c.x; o[5]=(f16)c.y; o[6]=(f16)c.z; o[7]=(f16)c.w;
    *(f16x8*)(A + (size_t)r * 1024 + seg * 8) = o;
}

// ---------------------------------------------------------------------------
// K4: init h/c state for level-0 rows (zero, or h0/c0 for un-reset t==0 rows)
// ---------------------------------------------------------------------------
__global__ __launch_bounds__(256) void k_init0(const float* __restrict__ c0,
                                               const float* __restrict__ h0,
                                               const int* __restrict__ resets,
                                               const int* __restrict__ rmap,
                                               const int* __restrict__ meta,
                                               f16* __restrict__ A,
                                               f16* __restrict__ Cb) {
    int gid = blockIdx.x * 256 + threadIdx.x;
    int r = gid >> 6, seg = gid & 63;
    if (r >= meta[M_CNT + 0]) return;   // level-0 rows occupy [0, cnt0)
    int tb = rmap[r];
    int t = tb >> 6, b = tb & 63;
    bool useinit = (t == 0) && (resets[b] == 0);
    f16x8 hv, cv;
    #pragma unroll
    for (int u = 0; u < 8; u++) {
        int j = seg * 8 + u;
        hv[u] = (f16)(useinit ? h0[b * H_ + j] : 0.0f);
        cv[u] = (f16)(useinit ? c0[b * H_ + j] : 0.0f);
    }
    *(f16x8*)(A + (size_t)r * 1024 + H_ + seg * 8) = hv;
    *(f16x8*)(Cb + (size_t)r * H_ + seg * 8) = cv;
}

// ---------------------------------------------------------------------------
// K5: fused level GEMM + LSTM epilogue.
// Tile: 64 rows x 64 hidden (=256 z-cols, 4 gates), K=1024, BK=32, 4 waves.
// ---------------------------------------------------------------------------
__global__ __launch_bounds__(256) void k_level(
    int level,
    const int* __restrict__ resets,
    const f16* __restrict__ W2t,      // [2048 cols][1024 k2]
    const float* __restrict__ bias,   // [2048]
    f16* __restrict__ Ab,             // [NROWS][1024]
    f16* __restrict__ Cb,             // [NROWS][512]
    const int* __restrict__ meta,
    const int* __restrict__ rmap,
    const int* __restrict__ rowid,
    float* __restrict__ ys)
{
    const int cnt = meta[M_CNT + level];
    const int row0 = blockIdx.x * 64;
    if (row0 >= cnt) return;
    const int off = meta[M_OFF + level];
    const int j0 = blockIdx.y * 64;

    __shared__ __align__(16) f16 As[64][32];
    __shared__ __align__(16) f16 Ws[256][32];

    const int tid  = threadIdx.x;
    const int lane = tid & 63;
    const int wave = tid >> 6;
    const int n = lane & 15;
    const int q = lane >> 4;

    fx4 acc[16];
    #pragma unroll
    for (int i = 0; i < 16; i++) acc[i] = (fx4){0.f, 0.f, 0.f, 0.f};

    const int ar  = tid >> 2;        // 0..63: A-tile row
    const int ach = tid & 3;         // 16B chunk within 64B k-slice
    const int gr_stage = row0 + ar;
    const int srow = off + (gr_stage < cnt ? gr_stage : 0);
    const f16* agp = Ab + (size_t)srow * 1024 + ach * 8;
    const int wc = tid >> 2;         // 0..63: local col within each gate's slab

    for (int k0 = 0; k0 < 1024; k0 += 32) {
        *(uint4*)(&As[ar][ach * 8]) = *(const uint4*)(agp + k0);
        #pragma unroll
        for (int s = 0; s < 4; s++) {  // s = gate
            const f16* wp = W2t + (size_t)(s * H_ + j0 + wc) * 1024 + k0 + ach * 8;
            *(uint4*)(&Ws[s * 64 + wc][ach * 8]) = *(const uint4*)wp;
        }
        __syncthreads();
        f16x8 a = *(const f16x8*)(&As[wave * 16 + n][q * 8]);
        #pragma unroll
        for (int ct = 0; ct < 16; ct++) {
            f16x8 bb = *(const f16x8*)(&Ws[ct * 16 + n][q * 8]);
            acc[ct] = __builtin_amdgcn_mfma_f32_16x16x32_f16(a, bb, acc[ct], 0, 0, 0);
        }
        __syncthreads();
    }

    // Epilogue: acc[gate*4 + jt][reg] = z for row (wave*16+q*4+reg), col gate*512 + j0 + jt*16 + n
    int tbs[4], succs[4], grows[4], valids[4];
    #pragma unroll
    for (int reg = 0; reg < 4; reg++) {
        int gr = row0 + wave * 16 + q * 4 + reg;
        valids[reg] = (gr < cnt);
        int grow = off + (gr < cnt ? gr : 0);
        grows[reg] = grow;
        int tb = rmap[grow];
        tbs[reg] = tb;
        int s = -1;
        if (gr < cnt && (tb >> 6) + 1 < T_ && resets[tb + B_] == 0) s = rowid[tb + B_];
        succs[reg] = s;
    }
    #pragma unroll
    for (int jt = 0; jt < 4; jt++) {
        int j = j0 + jt * 16 + n;
        float b_i = bias[j], b_f = bias[H_ + j], b_g = bias[2 * H_ + j], b_o = bias[3 * H_ + j];
        #pragma unroll
        for (int reg = 0; reg < 4; reg++) {
            if (!valids[reg]) continue;
            float zi = acc[jt][reg] + b_i;
            float zf = acc[4 + jt][reg] + b_f;
            float zg = acc[8 + jt][reg] + b_g;
            float zo = acc[12 + jt][reg] + b_o;
            float cp = (float)Cb[(size_t)grows[reg] * H_ + j];
            float iv = sigm(zi), fv = sigm(zf), gv = tanha(zg), ov = sigm(zo);
            float nc = fv * cp + iv * gv;
            float nh = ov * tanha(nc);            // tanh of UNclipped nc (matches ref order)
            float ncc = fminf(1.f, fmaxf(-1.f, nc));
            float nhc = fminf(1.f, fmaxf(-1.f, nh));
            ys[(size_t)tbs[reg] * H_ + j] = nhc;
            int s = succs[reg];
            if (s >= 0) {
                Ab[(size_t)s * 1024 + H_ + j] = (f16)nhc;
                Cb[(size_t)s * H_ + j] = (f16)ncc;
            }
        }
    }
}

// ---------------------------------------------------------------------------
// K6: sequential fp32 cleanup for any rows with level >= LMAX (normally none)
// ---------------------------------------------------------------------------
__global__ __launch_bounds__(256) void k_cleanup(
    const float* __restrict__ xs, const int* __restrict__ resets,
    const float* __restrict__ Wi, const float* __restrict__ Wh,
    const float* __restrict__ bias,
    const int* __restrict__ lvl, const int* __restrict__ rowid,
    const f16* __restrict__ Cb, float* __restrict__ ys)
{
    const int b = blockIdx.x;
    const int tid = threadIdx.x; // 256
    __shared__ float hs[H_], cs[H_];
    int last_t = -2;
    for (int t = 1; t < T_; t++) {
        if (lvl[t * B_ + b] < LMAX) continue;
        const int tb = t * B_ + b;
        if (last_t != t - 1) {
            for (int j = tid; j < H_; j += 256) {
                hs[j] = ys[(size_t)(tb - B_) * H_ + j];
                cs[j] = (float)Cb[(size_t)rowid[tb] * H_ + j];
            }
        }
        __syncthreads();
        float nh_[2], nc_[2];
        #pragma unroll
        for (int u = 0; u < 2; u++) {
            int j = tid + u * 256;
            float zi = bias[j], zf = bias[H_ + j], zg = bias[2 * H_ + j], zo = bias[3 * H_ + j];
            const float* xr = xs + (size_t)tb * H_;
            for (int k = 0; k < H_; k++) {
                float xk = xr[k], hk = hs[k];
                zi += xk * Wi[(size_t)k * 2048 + j]          + hk * Wh[(size_t)k * 2048 + j];
                zf += xk * Wi[(size_t)k * 2048 + H_ + j]     + hk * Wh[(size_t)k * 2048 + H_ + j];
                zg += xk * Wi[(size_t)k * 2048 + 2 * H_ + j] + hk * Wh[(size_t)k * 2048 + 2 * H_ + j];
                zo += xk * Wi[(size_t)k * 2048 + 3 * H_ + j] + hk * Wh[(size_t)k * 2048 + 3 * H_ + j];
            }
            float cp = cs[j];
            float iv = sigm(zi), fv = sigm(zf), gv = tanha(zg), ov = sigm(zo);
            float nc = fv * cp + iv * gv;
            float nh = ov * tanha(nc);
            nc_[u] = fminf(1.f, fmaxf(-1.f, nc));
            nh_[u] = fminf(1.f, fmaxf(-1.f, nh));
            ys[(size_t)tb * H_ + j] = nh_[u];
        }
        __syncthreads();
        #pragma unroll
        for (int u = 0; u < 2; u++) { int j = tid + u * 256; hs[j] = nh_[u]; cs[j] = nc_[u]; }
        last_t = t;
    }
}

// ---------------------------------------------------------------------------
// Fallback path (small workspace): 512 sequential fused step kernels, fp32
// ---------------------------------------------------------------------------
__global__ __launch_bounds__(256) void k_fb_init(const float* __restrict__ c0,
                                                 const float* __restrict__ h0,
                                                 float* __restrict__ cbuf,
                                                 float* __restrict__ hA) {
    int idx = blockIdx.x * 256 + threadIdx.x;
    if (idx >= B_ * H_) return;
    cbuf[idx] = c0[idx];
    hA[idx] = h0[idx];
}

__global__ __launch_bounds__(256) void k_fb_step(
    int t,
    const float* __restrict__ xs, const int* __restrict__ resets,
    const float* __restrict__ Wi, const float* __restrict__ Wh,
    const float* __restrict__ bias,
    const float* __restrict__ hin, float* __restrict__ hout,
    float* __restrict__ cbuf, float* __restrict__ ys)
{
    int idx = blockIdx.x * 256 + threadIdx.x;  // B*H
    int b = idx >> 9, j = idx & 511;
    int tb = t * B_ + b;
    bool rst = resets[tb] != 0;
    float zi = bias[j], zf = bias[H_ + j], zg = bias[2 * H_ + j], zo = bias[3 * H_ + j];
    const float* xr = xs + (size_t)tb * H_;
    for (int k = 0; k < H_; k++) {
        float xk = xr[k];
        zi += xk * Wi[(size_t)k * 2048 + j];
        zf += xk * Wi[(size_t)k * 2048 + H_ + j];
        zg += xk * Wi[(size_t)k * 2048 + 2 * H_ + j];
        zo += xk * Wi[(size_t)k * 2048 + 3 * H_ + j];
    }
    if (!rst) {
        const float* hr = hin + b * H_;
        for (int k = 0; k < H_; k++) {
            float hk = hr[k];
            zi += hk * Wh[(size_t)k * 2048 + j];
            zf += hk * Wh[(size_t)k * 2048 + H_ + j];
            zg += hk * Wh[(size_t)k * 2048 + 2 * H_ + j];
            zo += hk * Wh[(size_t)k * 2048 + 3 * H_ + j];
        }
    }
    float cp = rst ? 0.f : cbuf[idx];
    float iv = sigm(zi), fv = sigm(zf), gv = tanha(zg), ov = sigm(zo);
    float nc = fv * cp + iv * gv;
    float nh = ov * tanha(nc);
    float ncc = fminf(1.f, fmaxf(-1.f, nc));
    float nhc = fminf(1.f, fmaxf(-1.f, nh));
    cbuf[idx] = ncc;
    hout[idx] = nhc;
    ys[(size_t)tb * H_ + j] = nhc;
}

// ---------------------------------------------------------------------------
extern "C" void kernel_launch(void* const* d_in, const int* in_sizes, int n_in,
                              void* d_out, int out_size, void* d_ws, size_t ws_size,
                              hipStream_t stream) {
    const float* xs    = (const float*)d_in[0];
    const int*   resets= (const int*)d_in[1];
    const float* c0    = (const float*)d_in[2];
    const float* h0    = (const float*)d_in[3];
    const float* Wi    = (const float*)d_in[4];
    const float* Wh    = (const float*)d_in[5];
    const float* bias  = (const float*)d_in[6];
    float* ys = (float*)d_out;
    char* ws = (char*)d_ws;

    const size_t OFF_A    = 0;                              // 32768*1024*2 = 64 MiB
    const size_t OFF_C    = 67108864;                       // 32768*512*2  = 32 MiB
    const size_t OFF_W2T  = 100663296;                      // 2048*1024*2  = 4 MiB
    const size_t OFF_LVL  = 104857600;                      // 128 KiB
    const size_t OFF_RID  = 104988672;                      // 128 KiB
    const size_t OFF_RMAP = 105119744;                      // 128 KiB
    const size_t OFF_META = 105250816;                      // 512 B
    const size_t NEEDED   = 105251328;

    if (ws_size >= NEEDED) {
        f16* A    = (f16*)(ws + OFF_A);
        f16* Cb   = (f16*)(ws + OFF_C);
        f16* W2t  = (f16*)(ws + OFF_W2T);
        int* lvl  = (int*)(ws + OFF_LVL);
        int* rid  = (int*)(ws + OFF_RID);
        int* rmap = (int*)(ws + OFF_RMAP);
        int* meta = (int*)(ws + OFF_META);

        k_prepw<<<dim3(32, 16), dim3(256), 0, stream>>>(Wi, Wh, W2t);
        k_scan<<<dim3(1), dim3(64), 0, stream>>>(resets, lvl, meta);
        k_build<<<dim3(NROWS / 256), dim3(256), 0, stream>>>(lvl, meta, rid, rmap);
        k_fillx<<<dim3(NROWS * 64 / 256), dim3(256), 0, stream>>>(xs, rmap, A);
        k_init0<<<dim3(NROWS * 64 / 256), dim3(256), 0, stream>>>(c0, h0, resets, rmap, meta, A, Cb);
        for (int k = 0; k < LMAX; k++) {
            int maxr = 64 * ((512 + k) / (k + 1));   // upper bound on rows at level k
            dim3 grid((maxr + 63) / 64, 8);
            k_level<<<grid, dim3(256), 0, stream>>>(k, resets, W2t, bias, A, Cb,
                                                    meta, rmap, rid, ys);
        }
        k_cleanup<<<dim3(64), dim3(256), 0, stream>>>(xs, resets, Wi, Wh, bias,
                                                      lvl, rid, Cb, ys);
    } else {
        // Fallback: sequential per-timestep fused kernels (fp32)
        float* cbuf = (float*)(ws);
        float* hA   = (float*)(ws + 131072);
        float* hB   = (float*)(ws + 262144);
        k_fb_init<<<dim3(128), dim3(256), 0, stream>>>(c0, h0, cbuf, hA);
        for (int t = 0; t < T_; t++) {
            const float* hin = (t & 1) ? hB : hA;
            float* hout      = (t & 1) ? hA : hB;
            k_fb_step<<<dim3(128), dim3(256), 0, stream>>>(t, xs, resets, Wi, Wh, bias,
                                                           hin, hout, cbuf, ys);
        }
    }
}

// Round 2
// 1126.492 us; speedup vs baseline: 1.5121x; 1.5121x over previous
//
#include <hip/hip_runtime.h>

#define T_ 512
#define B_ 64
#define H_ 512
#define LMAX 28
#define NROWS (T_*B_)   // 32768

typedef _Float16 f16;
typedef __attribute__((ext_vector_type(8))) _Float16 f16x8;
typedef __attribute__((ext_vector_type(4))) float fx4;

#define M_CNT 0
#define M_OFF 32

__device__ __forceinline__ float sigm(float z)  { return 1.0f / (1.0f + __expf(-z)); }
__device__ __forceinline__ float tanha(float z) { return 2.0f / (1.0f + __expf(-2.0f * z)) - 1.0f; }

// ---------------------------------------------------------------------------
// K0: pack [Wi;Wh] (fp32, (1024 rows k2) x (2048 cols)) into W2t fp16 [col][k2]
// ---------------------------------------------------------------------------
__global__ __launch_bounds__(256) void k_prepw(const float* __restrict__ Wi,
                                               const float* __restrict__ Wh,
                                               f16* __restrict__ W2t) {
    __shared__ float tile[64][65];
    const int c0  = blockIdx.x * 64;   // col tile
    const int k20 = blockIdx.y * 64;   // k2 tile
    const int tid = threadIdx.x;
    #pragma unroll
    for (int s = 0; s < 16; s++) {
        int k2r = s * 4 + (tid >> 6);
        int c   = tid & 63;
        int k2  = k20 + k2r;
        float v = (k2 < H_) ? Wi[(size_t)k2 * 2048 + c0 + c]
                            : Wh[(size_t)(k2 - H_) * 2048 + c0 + c];
        tile[c][k2r] = v;
    }
    __syncthreads();
    const int c  = tid >> 2;
    const int ch = tid & 3;
    f16 tmp[16];
    #pragma unroll
    for (int u = 0; u < 16; u++) tmp[u] = (f16)tile[c][ch * 16 + u];
    f16* dst = W2t + (size_t)(c0 + c) * 1024 + k20 + ch * 16;
    *(uint4*)(dst)     = *(const uint4*)(tmp);
    *(uint4*)(dst + 8) = *(const uint4*)(tmp + 8);
}

// ---------------------------------------------------------------------------
// K1: single-block scan + bucket build, all in LDS, no atomics.
//  Phase 1: reset bitmasks per t via ballot.
//  Phase 2: per-b level walk, per-(level,b) counts (unique LDS addrs).
//  Phase 3: per-(level,b) deterministic offsets.
//  Phase 4: per-b slot assignment -> rowid / rmap.
// ---------------------------------------------------------------------------
__global__ __launch_bounds__(256) void k_scan_build(const int* __restrict__ resets,
                                                    int* __restrict__ lvl,
                                                    int* __restrict__ meta,
                                                    int* __restrict__ rowid,
                                                    int* __restrict__ rmap) {
    __shared__ unsigned long long mask[T_];          // 4 KiB
    __shared__ int cnt[LMAX + 1][B_];                // 7.25 KiB
    __shared__ int cur[LMAX + 1][B_];                // 7.25 KiB
    __shared__ int cntk[LMAX + 1], offk[LMAX + 1];

    const int tid  = threadIdx.x;
    const int lane = tid & 63;
    const int wave = tid >> 6;

    // Phase 1: mask[t] bit b = resets[t*B+b] != 0   (coalesced, 4 waves)
    for (int t = wave; t < T_; t += 4) {
        int r = resets[t * B_ + lane];
        unsigned long long m = __ballot(r != 0);
        if (lane == 0) mask[t] = m;
    }
    // zero counters
    for (int i = tid; i < (LMAX + 1) * B_; i += 256) ((int*)cnt)[i] = 0;
    __syncthreads();

    // Phase 2: per-b level walk; write lvl (coalesced); count per (level,b)
    if (tid < B_) {
        const int b = tid;
        int prev = 0;
        for (int t = 0; t < T_; t++) {
            int rst = (int)((mask[t] >> b) & 1ULL);
            int lv = (t == 0) ? 0 : (rst ? 0 : prev + 1);
            int kk = lv < LMAX ? lv : LMAX;
            cnt[kk][b] += 1;
            lvl[t * B_ + b] = lv;
            prev = lv;
        }
    }
    __syncthreads();

    // Phase 3: totals per level, prefix offsets, per-(level,b) bases
    if (tid <= LMAX) {
        const int k = tid;
        int acc = 0;
        for (int b = 0; b < B_; b++) { cur[k][b] = acc; acc += cnt[k][b]; }
        cntk[k] = acc;
    }
    __syncthreads();
    if (tid == 0) {
        int acc = 0;
        for (int k = 0; k <= LMAX; k++) { offk[k] = acc; acc += cntk[k]; }
    }
    __syncthreads();
    if (tid <= LMAX) {
        const int k = tid;
        for (int b = 0; b < B_; b++) cur[k][b] += offk[k];
        meta[M_CNT + k] = cntk[k];
        meta[M_OFF + k] = offk[k];
    }
    __syncthreads();

    // Phase 4: assign slots (deterministic, no atomics)
    if (tid < B_) {
        const int b = tid;
        int prev = 0;
        for (int t = 0; t < T_; t++) {
            int rst = (int)((mask[t] >> b) & 1ULL);
            int lv = (t == 0) ? 0 : (rst ? 0 : prev + 1);
            int kk = lv < LMAX ? lv : LMAX;
            int r = cur[kk][b];
            cur[kk][b] = r + 1;
            int tb = t * B_ + b;
            rowid[tb] = r;
            rmap[r] = tb;
            prev = lv;
        }
    }
}

// ---------------------------------------------------------------------------
// K2: gather x rows (fp32 -> fp16) into A[:,0:512]; init h/c for level-0 rows
// ---------------------------------------------------------------------------
__global__ __launch_bounds__(256) void k_fill(const float* __restrict__ xs,
                                              const float* __restrict__ c0,
                                              const float* __restrict__ h0,
                                              const int* __restrict__ resets,
                                              const int* __restrict__ rmap,
                                              const int* __restrict__ meta,
                                              f16* __restrict__ A,
                                              f16* __restrict__ Cb) {
    int gid = blockIdx.x * 256 + threadIdx.x;  // NROWS*64 threads
    int r = gid >> 6, seg = gid & 63;
    int tb = rmap[r];
    const float4* src = (const float4*)(xs + (size_t)tb * H_ + seg * 8);
    float4 a = src[0];
    float4 c = src[1];
    f16x8 o;
    o[0]=(f16)a.x; o[1]=(f16)a.y; o[2]=(f16)a.z; o[3]=(f16)a.w;
    o[4]=(f16)c.x; o[5]=(f16)c.y; o[6]=(f16)c.z; o[7]=(f16)c.w;
    *(f16x8*)(A + (size_t)r * 1024 + seg * 8) = o;

    if (r < meta[M_CNT + 0]) {   // level-0 rows occupy [0, cnt0)
        int t = tb >> 6, b = tb & 63;
        bool useinit = (t == 0) && (resets[b] == 0);
        f16x8 hv, cv;
        #pragma unroll
        for (int u = 0; u < 8; u++) {
            int j = seg * 8 + u;
            hv[u] = (f16)(useinit ? h0[b * H_ + j] : 0.0f);
            cv[u] = (f16)(useinit ? c0[b * H_ + j] : 0.0f);
        }
        *(f16x8*)(A + (size_t)r * 1024 + H_ + seg * 8) = hv;
        *(f16x8*)(Cb + (size_t)r * H_ + seg * 8) = cv;
    }
}

// ---------------------------------------------------------------------------
// K3: fused level GEMM + LSTM epilogue.
// Tile: 64 rows x 64 hidden (=256 z-cols, 4 gates), K=1024, BK=32, 4 waves.
// ---------------------------------------------------------------------------
__global__ __launch_bounds__(256) void k_level(
    int level,
    const int* __restrict__ resets,
    const f16* __restrict__ W2t,      // [2048 cols][1024 k2]
    const float* __restrict__ bias,   // [2048]
    f16* __restrict__ Ab,             // [NROWS][1024]
    f16* __restrict__ Cb,             // [NROWS][512]
    const int* __restrict__ meta,
    const int* __restrict__ rmap,
    const int* __restrict__ rowid,
    float* __restrict__ ys)
{
    const int cnt = meta[M_CNT + level];
    const int row0 = blockIdx.x * 64;
    if (row0 >= cnt) return;
    const int off = meta[M_OFF + level];
    const int j0 = blockIdx.y * 64;

    __shared__ __align__(16) f16 As[64][32];
    __shared__ __align__(16) f16 Ws[256][32];

    const int tid  = threadIdx.x;
    const int lane = tid & 63;
    const int wave = tid >> 6;
    const int n = lane & 15;
    const int q = lane >> 4;

    fx4 acc[16];
    #pragma unroll
    for (int i = 0; i < 16; i++) acc[i] = (fx4){0.f, 0.f, 0.f, 0.f};

    const int ar  = tid >> 2;        // 0..63: A-tile row
    const int ach = tid & 3;         // 16B chunk within 64B k-slice
    const int gr_stage = row0 + ar;
    const int srow = off + (gr_stage < cnt ? gr_stage : 0);
    const f16* agp = Ab + (size_t)srow * 1024 + ach * 8;
    const int wc = tid >> 2;         // 0..63: local col within each gate's slab

    for (int k0 = 0; k0 < 1024; k0 += 32) {
        *(uint4*)(&As[ar][ach * 8]) = *(const uint4*)(agp + k0);
        #pragma unroll
        for (int s = 0; s < 4; s++) {  // s = gate
            const f16* wp = W2t + (size_t)(s * H_ + j0 + wc) * 1024 + k0 + ach * 8;
            *(uint4*)(&Ws[s * 64 + wc][ach * 8]) = *(const uint4*)wp;
        }
        __syncthreads();
        f16x8 a = *(const f16x8*)(&As[wave * 16 + n][q * 8]);
        #pragma unroll
        for (int ct = 0; ct < 16; ct++) {
            f16x8 bb = *(const f16x8*)(&Ws[ct * 16 + n][q * 8]);
            acc[ct] = __builtin_amdgcn_mfma_f32_16x16x32_f16(a, bb, acc[ct], 0, 0, 0);
        }
        __syncthreads();
    }

    // Epilogue: acc[gate*4 + jt][reg] = z for row (wave*16+q*4+reg), col gate*512 + j0 + jt*16 + n
    int tbs[4], succs[4], grows[4], valids[4];
    #pragma unroll
    for (int reg = 0; reg < 4; reg++) {
        int gr = row0 + wave * 16 + q * 4 + reg;
        valids[reg] = (gr < cnt);
        int grow = off + (gr < cnt ? gr : 0);
        grows[reg] = grow;
        int tb = rmap[grow];
        tbs[reg] = tb;
        int s = -1;
        if (gr < cnt && (tb >> 6) + 1 < T_ && resets[tb + B_] == 0) s = rowid[tb + B_];
        succs[reg] = s;
    }
    #pragma unroll
    for (int jt = 0; jt < 4; jt++) {
        int j = j0 + jt * 16 + n;
        float b_i = bias[j], b_f = bias[H_ + j], b_g = bias[2 * H_ + j], b_o = bias[3 * H_ + j];
        #pragma unroll
        for (int reg = 0; reg < 4; reg++) {
            if (!valids[reg]) continue;
            float zi = acc[jt][reg] + b_i;
            float zf = acc[4 + jt][reg] + b_f;
            float zg = acc[8 + jt][reg] + b_g;
            float zo = acc[12 + jt][reg] + b_o;
            float cp = (float)Cb[(size_t)grows[reg] * H_ + j];
            float iv = sigm(zi), fv = sigm(zf), gv = tanha(zg), ov = sigm(zo);
            float nc = fv * cp + iv * gv;
            float nh = ov * tanha(nc);            // tanh of UNclipped nc (matches ref order)
            float ncc = fminf(1.f, fmaxf(-1.f, nc));
            float nhc = fminf(1.f, fmaxf(-1.f, nh));
            ys[(size_t)tbs[reg] * H_ + j] = nhc;
            int s = succs[reg];
            if (s >= 0) {
                Ab[(size_t)s * 1024 + H_ + j] = (f16)nhc;
                Cb[(size_t)s * H_ + j] = (f16)ncc;
            }
        }
    }
}

// ---------------------------------------------------------------------------
// K4: sequential fp32 cleanup for rows with level >= LMAX (normally none):
//     early-exits on meta count so the common case costs one scalar load.
// ---------------------------------------------------------------------------
__global__ __launch_bounds__(256) void k_cleanup(
    const float* __restrict__ xs, const int* __restrict__ resets,
    const float* __restrict__ Wi, const float* __restrict__ Wh,
    const float* __restrict__ bias,
    const int* __restrict__ lvl, const int* __restrict__ rowid,
    const int* __restrict__ meta,
    const f16* __restrict__ Cb, float* __restrict__ ys)
{
    if (meta[M_CNT + LMAX] == 0) return;   // expected case: nothing to do
    const int b = blockIdx.x;
    const int tid = threadIdx.x; // 256
    __shared__ float hs[H_], cs[H_];
    int last_t = -2;
    for (int t = 1; t < T_; t++) {
        if (lvl[t * B_ + b] < LMAX) continue;
        const int tb = t * B_ + b;
        if (last_t != t - 1) {
            for (int j = tid; j < H_; j += 256) {
                hs[j] = ys[(size_t)(tb - B_) * H_ + j];
                cs[j] = (float)Cb[(size_t)rowid[tb] * H_ + j];
            }
        }
        __syncthreads();
        float nh_[2], nc_[2];
        #pragma unroll
        for (int u = 0; u < 2; u++) {
            int j = tid + u * 256;
            float zi = bias[j], zf = bias[H_ + j], zg = bias[2 * H_ + j], zo = bias[3 * H_ + j];
            const float* xr = xs + (size_t)tb * H_;
            for (int k = 0; k < H_; k++) {
                float xk = xr[k], hk = hs[k];
                zi += xk * Wi[(size_t)k * 2048 + j]          + hk * Wh[(size_t)k * 2048 + j];
                zf += xk * Wi[(size_t)k * 2048 + H_ + j]     + hk * Wh[(size_t)k * 2048 + H_ + j];
                zg += xk * Wi[(size_t)k * 2048 + 2 * H_ + j] + hk * Wh[(size_t)k * 2048 + 2 * H_ + j];
                zo += xk * Wi[(size_t)k * 2048 + 3 * H_ + j] + hk * Wh[(size_t)k * 2048 + 3 * H_ + j];
            }
            float cp = cs[j];
            float iv = sigm(zi), fv = sigm(zf), gv = tanha(zg), ov = sigm(zo);
            float nc = fv * cp + iv * gv;
            float nh = ov * tanha(nc);
            nc_[u] = fminf(1.f, fmaxf(-1.f, nc));
            nh_[u] = fminf(1.f, fmaxf(-1.f, nh));
            ys[(size_t)tb * H_ + j] = nh_[u];
        }
        __syncthreads();
        #pragma unroll
        for (int u = 0; u < 2; u++) { int j = tid + u * 256; hs[j] = nh_[u]; cs[j] = nc_[u]; }
        last_t = t;
    }
}

// ---------------------------------------------------------------------------
// Fallback path (small workspace): 512 sequential fused step kernels, fp32
// ---------------------------------------------------------------------------
__global__ __launch_bounds__(256) void k_fb_init(const float* __restrict__ c0,
                                                 const float* __restrict__ h0,
                                                 float* __restrict__ cbuf,
                                                 float* __restrict__ hA) {
    int idx = blockIdx.x * 256 + threadIdx.x;
    if (idx >= B_ * H_) return;
    cbuf[idx] = c0[idx];
    hA[idx] = h0[idx];
}

__global__ __launch_bounds__(256) void k_fb_step(
    int t,
    const float* __restrict__ xs, const int* __restrict__ resets,
    const float* __restrict__ Wi, const float* __restrict__ Wh,
    const float* __restrict__ bias,
    const float* __restrict__ hin, float* __restrict__ hout,
    float* __restrict__ cbuf, float* __restrict__ ys)
{
    int idx = blockIdx.x * 256 + threadIdx.x;  // B*H
    int b = idx >> 9, j = idx & 511;
    int tb = t * B_ + b;
    bool rst = resets[tb] != 0;
    float zi = bias[j], zf = bias[H_ + j], zg = bias[2 * H_ + j], zo = bias[3 * H_ + j];
    const float* xr = xs + (size_t)tb * H_;
    for (int k = 0; k < H_; k++) {
        float xk = xr[k];
        zi += xk * Wi[(size_t)k * 2048 + j];
        zf += xk * Wi[(size_t)k * 2048 + H_ + j];
        zg += xk * Wi[(size_t)k * 2048 + 2 * H_ + j];
        zo += xk * Wi[(size_t)k * 2048 + 3 * H_ + j];
    }
    if (!rst) {
        const float* hr = hin + b * H_;
        for (int k = 0; k < H_; k++) {
            float hk = hr[k];
            zi += hk * Wh[(size_t)k * 2048 + j];
            zf += hk * Wh[(size_t)k * 2048 + H_ + j];
            zg += hk * Wh[(size_t)k * 2048 + 2 * H_ + j];
            zo += hk * Wh[(size_t)k * 2048 + 3 * H_ + j];
        }
    }
    float cp = rst ? 0.f : cbuf[idx];
    float iv = sigm(zi), fv = sigm(zf), gv = tanha(zg), ov = sigm(zo);
    float nc = fv * cp + iv * gv;
    float nh = ov * tanha(nc);
    float ncc = fminf(1.f, fmaxf(-1.f, nc));
    float nhc = fminf(1.f, fmaxf(-1.f, nh));
    cbuf[idx] = ncc;
    hout[idx] = nhc;
    ys[(size_t)tb * H_ + j] = nhc;
}

// ---------------------------------------------------------------------------
extern "C" void kernel_launch(void* const* d_in, const int* in_sizes, int n_in,
                              void* d_out, int out_size, void* d_ws, size_t ws_size,
                              hipStream_t stream) {
    const float* xs    = (const float*)d_in[0];
    const int*   resets= (const int*)d_in[1];
    const float* c0    = (const float*)d_in[2];
    const float* h0    = (const float*)d_in[3];
    const float* Wi    = (const float*)d_in[4];
    const float* Wh    = (const float*)d_in[5];
    const float* bias  = (const float*)d_in[6];
    float* ys = (float*)d_out;
    char* ws = (char*)d_ws;

    const size_t OFF_A    = 0;                              // 32768*1024*2 = 64 MiB
    const size_t OFF_C    = 67108864;                       // 32768*512*2  = 32 MiB
    const size_t OFF_W2T  = 100663296;                      // 2048*1024*2  = 4 MiB
    const size_t OFF_LVL  = 104857600;                      // 128 KiB
    const size_t OFF_RID  = 104988672;                      // 128 KiB
    const size_t OFF_RMAP = 105119744;                      // 128 KiB
    const size_t OFF_META = 105250816;                      // 512 B
    const size_t NEEDED   = 105251328;

    if (ws_size >= NEEDED) {
        f16* A    = (f16*)(ws + OFF_A);
        f16* Cb   = (f16*)(ws + OFF_C);
        f16* W2t  = (f16*)(ws + OFF_W2T);
        int* lvl  = (int*)(ws + OFF_LVL);
        int* rid  = (int*)(ws + OFF_RID);
        int* rmap = (int*)(ws + OFF_RMAP);
        int* meta = (int*)(ws + OFF_META);

        k_prepw<<<dim3(32, 16), dim3(256), 0, stream>>>(Wi, Wh, W2t);
        k_scan_build<<<dim3(1), dim3(256), 0, stream>>>(resets, lvl, meta, rid, rmap);
        k_fill<<<dim3(NROWS * 64 / 256), dim3(256), 0, stream>>>(xs, c0, h0, resets, rmap, meta, A, Cb);
        for (int k = 0; k < LMAX; k++) {
            int maxr = 64 * ((512 + k) / (k + 1));   // upper bound on rows at level k
            dim3 grid((maxr + 63) / 64, 8);
            k_level<<<grid, dim3(256), 0, stream>>>(k, resets, W2t, bias, A, Cb,
                                                    meta, rmap, rid, ys);
        }
        k_cleanup<<<dim3(64), dim3(256), 0, stream>>>(xs, resets, Wi, Wh, bias,
                                                      lvl, rid, meta, Cb, ys);
    } else {
        // Fallback: sequential per-timestep fused kernels (fp32)
        float* cbuf = (float*)(ws);
        float* hA   = (float*)(ws + 131072);
        float* hB   = (float*)(ws + 262144);
        k_fb_init<<<dim3(128), dim3(256), 0, stream>>>(c0, h0, cbuf, hA);
        for (int t = 0; t < T_; t++) {
            const float* hin = (t & 1) ? hB : hA;
            float* hout      = (t & 1) ? hA : hB;
            k_fb_step<<<dim3(128), dim3(256), 0, stream>>>(t, xs, resets, Wi, Wh, bias,
                                                           hin, hout, cbuf, ys);
        }
    }
}

// Round 3
// 850.436 us; speedup vs baseline: 2.0029x; 1.3246x over previous
//
#include <hip/hip_runtime.h>

#define T_ 512
#define B_ 64
#define H_ 512
#define LMAX 20
#define NROWS (T_*B_)   // 32768

typedef _Float16 f16;
typedef __attribute__((ext_vector_type(2))) _Float16 f16x2;
typedef __attribute__((ext_vector_type(8))) _Float16 f16x8;
typedef __attribute__((ext_vector_type(4))) float fx4;

#define M_CNT 0
#define M_OFF 32

__device__ __forceinline__ float sigm(float z)  { return 1.0f / (1.0f + __expf(-z)); }
__device__ __forceinline__ float tanha(float z) { return 2.0f / (1.0f + __expf(-2.0f * z)) - 1.0f; }

// ---------------------------------------------------------------------------
// K0: pack [Wi;Wh] (fp32, (1024 rows k2) x (2048 cols)) into W2t fp16 [col][k2]
// k2 in [0,512) = Wi rows, k2 in [512,1024) = Wh rows.
// ---------------------------------------------------------------------------
__global__ __launch_bounds__(256) void k_prepw(const float* __restrict__ Wi,
                                               const float* __restrict__ Wh,
                                               f16* __restrict__ W2t) {
    __shared__ float tile[64][65];
    const int c0  = blockIdx.x * 64;   // col tile
    const int k20 = blockIdx.y * 64;   // k2 tile
    const int tid = threadIdx.x;
    #pragma unroll
    for (int s = 0; s < 16; s++) {
        int k2r = s * 4 + (tid >> 6);
        int c   = tid & 63;
        int k2  = k20 + k2r;
        float v = (k2 < H_) ? Wi[(size_t)k2 * 2048 + c0 + c]
                            : Wh[(size_t)(k2 - H_) * 2048 + c0 + c];
        tile[c][k2r] = v;
    }
    __syncthreads();
    const int c  = tid >> 2;
    const int ch = tid & 3;
    f16 tmp[16];
    #pragma unroll
    for (int u = 0; u < 16; u++) tmp[u] = (f16)tile[c][ch * 16 + u];
    f16* dst = W2t + (size_t)(c0 + c) * 1024 + k20 + ch * 16;
    *(uint4*)(dst)     = *(const uint4*)(tmp);
    *(uint4*)(dst + 8) = *(const uint4*)(tmp + 8);
}

// ---------------------------------------------------------------------------
// K1: single-block scan + bucket build, all in LDS, no atomics.
// ---------------------------------------------------------------------------
__global__ __launch_bounds__(256) void k_scan_build(const int* __restrict__ resets,
                                                    int* __restrict__ lvl,
                                                    int* __restrict__ meta,
                                                    int* __restrict__ rowid,
                                                    int* __restrict__ rmap) {
    __shared__ unsigned long long mask[T_];
    __shared__ int cnt[LMAX + 1][B_];
    __shared__ int cur[LMAX + 1][B_];
    __shared__ int cntk[LMAX + 1], offk[LMAX + 1];

    const int tid  = threadIdx.x;
    const int lane = tid & 63;
    const int wave = tid >> 6;

    for (int t = wave; t < T_; t += 4) {
        int r = resets[t * B_ + lane];
        unsigned long long m = __ballot(r != 0);
        if (lane == 0) mask[t] = m;
    }
    for (int i = tid; i < (LMAX + 1) * B_; i += 256) ((int*)cnt)[i] = 0;
    __syncthreads();

    if (tid < B_) {
        const int b = tid;
        int prev = 0;
        for (int t = 0; t < T_; t++) {
            int rst = (int)((mask[t] >> b) & 1ULL);
            int lv = (t == 0) ? 0 : (rst ? 0 : prev + 1);
            int kk = lv < LMAX ? lv : LMAX;
            cnt[kk][b] += 1;
            lvl[t * B_ + b] = lv;
            prev = lv;
        }
    }
    __syncthreads();

    if (tid <= LMAX) {
        const int k = tid;
        int acc = 0;
        for (int b = 0; b < B_; b++) { cur[k][b] = acc; acc += cnt[k][b]; }
        cntk[k] = acc;
    }
    __syncthreads();
    if (tid == 0) {
        int acc = 0;
        for (int k = 0; k <= LMAX; k++) { offk[k] = acc; acc += cntk[k]; }
    }
    __syncthreads();
    if (tid <= LMAX) {
        const int k = tid;
        for (int b = 0; b < B_; b++) cur[k][b] += offk[k];
        meta[M_CNT + k] = cntk[k];
        meta[M_OFF + k] = offk[k];
    }
    __syncthreads();

    if (tid < B_) {
        const int b = tid;
        int prev = 0;
        for (int t = 0; t < T_; t++) {
            int rst = (int)((mask[t] >> b) & 1ULL);
            int lv = (t == 0) ? 0 : (rst ? 0 : prev + 1);
            int kk = lv < LMAX ? lv : LMAX;
            int r = cur[kk][b];
            cur[kk][b] = r + 1;
            int tb = t * B_ + b;
            rowid[tb] = r;
            rmap[r] = tb;
            prev = lv;
        }
    }
}

// ===========================================================================
// PATH A kernels
// ===========================================================================

// A1: linear fp32 -> f16 cast of xs into X [NROWS][512] (tb order, no gather)
__global__ __launch_bounds__(256) void k_xcast(const float* __restrict__ xs,
                                               f16* __restrict__ X) {
    int gid = blockIdx.x * 256 + threadIdx.x;
    const float4* src = (const float4*)(xs) + (size_t)gid * 2;
    float4 a = src[0], c = src[1];
    f16x8 o;
    o[0]=(f16)a.x; o[1]=(f16)a.y; o[2]=(f16)a.z; o[3]=(f16)a.w;
    o[4]=(f16)c.x; o[5]=(f16)c.y; o[6]=(f16)c.z; o[7]=(f16)c.w;
    *(f16x8*)(X + (size_t)gid * 8) = o;
}

// A2: hz0[b][j] = sum_k h0[b][k] * Wh[k][j]  (f16 weights via W2t Wh-part)
__global__ __launch_bounds__(256) void k_hz0(const float* __restrict__ h0,
                                             const f16* __restrict__ W2t,
                                             float* __restrict__ hz0) {
    const int b = blockIdx.x >> 3;
    const int j = ((blockIdx.x & 7) * 256) + threadIdx.x;
    __shared__ float h[H_];
    for (int k = threadIdx.x; k < H_; k += 256) h[k] = h0[b * H_ + k];
    __syncthreads();
    const f16* wr = W2t + (size_t)j * 1024 + 512;
    float acc = 0.f;
    for (int k = 0; k < H_; k += 8) {
        f16x8 w = *(const f16x8*)(wr + k);
        #pragma unroll
        for (int u = 0; u < 8; u++) acc += h[k + u] * (float)w[u];
    }
    hz0[(size_t)b * 2048 + j] = acc;
}

// A3: dense XZ GEMM: XZ[NROWS][2048] = X[NROWS][512] @ Wi  (f16, fp32 acc)
// 128x128 tile, BK=32, 4 waves (2x2), padded LDS.
__global__ __launch_bounds__(256) void k_xz(const f16* __restrict__ X,
                                            const f16* __restrict__ W2t,
                                            f16* __restrict__ XZ) {
    const int r0 = blockIdx.x * 128;
    const int j0 = blockIdx.y * 128;
    __shared__ __align__(16) f16 As[128][40];
    __shared__ __align__(16) f16 Bs[128][40];
    const int tid  = threadIdx.x;
    const int lane = tid & 63;
    const int wave = tid >> 6;
    const int wm = wave & 1, wn = wave >> 1;
    const int n = lane & 15, q = lane >> 4;

    fx4 acc[4][4];
    #pragma unroll
    for (int i = 0; i < 4; i++)
        #pragma unroll
        for (int jj = 0; jj < 4; jj++) acc[i][jj] = (fx4){0.f,0.f,0.f,0.f};

    const int arow = tid >> 2, ach = tid & 3;
    const f16* xa = X + (size_t)(r0 + arow) * 512 + ach * 8;
    const f16* xb = X + (size_t)(r0 + 64 + arow) * 512 + ach * 8;
    const f16* wa = W2t + (size_t)(j0 + arow) * 1024 + ach * 8;
    const f16* wb = W2t + (size_t)(j0 + 64 + arow) * 1024 + ach * 8;

    for (int k0 = 0; k0 < 512; k0 += 32) {
        *(uint4*)(&As[arow][ach * 8])      = *(const uint4*)(xa + k0);
        *(uint4*)(&As[64 + arow][ach * 8]) = *(const uint4*)(xb + k0);
        *(uint4*)(&Bs[arow][ach * 8])      = *(const uint4*)(wa + k0);
        *(uint4*)(&Bs[64 + arow][ach * 8]) = *(const uint4*)(wb + k0);
        __syncthreads();
        f16x8 af[4], bf[4];
        #pragma unroll
        for (int mt = 0; mt < 4; mt++) af[mt] = *(const f16x8*)(&As[wm*64 + mt*16 + n][q*8]);
        #pragma unroll
        for (int nt = 0; nt < 4; nt++) bf[nt] = *(const f16x8*)(&Bs[wn*64 + nt*16 + n][q*8]);
        #pragma unroll
        for (int mt = 0; mt < 4; mt++)
            #pragma unroll
            for (int nt = 0; nt < 4; nt++)
                acc[mt][nt] = __builtin_amdgcn_mfma_f32_16x16x32_f16(af[mt], bf[nt], acc[mt][nt], 0, 0, 0);
        __syncthreads();
    }
    #pragma unroll
    for (int mt = 0; mt < 4; mt++)
        #pragma unroll
        for (int nt = 0; nt < 4; nt++)
            #pragma unroll
            for (int reg = 0; reg < 4; reg++) {
                int row = r0 + wm * 64 + mt * 16 + q * 4 + reg;
                int col = j0 + wn * 64 + nt * 16 + n;
                XZ[(size_t)row * 2048 + col] = (f16)acc[mt][nt][reg];
            }
}

// A4: level-0 epilogue (no GEMM): z = XZ + bias (+ hz0 for t==0 non-reset)
__global__ __launch_bounds__(256) void k_lvl0epi(
    const f16* __restrict__ XZ, const float* __restrict__ hz0,
    const float* __restrict__ c0, const float* __restrict__ bias,
    const int* __restrict__ resets, const int* __restrict__ meta,
    const int* __restrict__ rmap, const int* __restrict__ rowid,
    f16* __restrict__ Hb, f16* __restrict__ Cb, float* __restrict__ ys)
{
    const int r = blockIdx.x;
    if (r >= meta[M_CNT + 0]) return;
    const int tb = rmap[r];
    const int t = tb >> 6, b = tb & 63;
    const bool useinit = (t == 0) && (resets[b] == 0);
    int s = -1;
    if (t + 1 < T_ && resets[tb + B_] == 0) s = rowid[tb + B_];

    const int jh = threadIdx.x * 2;
    const f16* zr = XZ + (size_t)tb * 2048;
    f16x2 vi = *(const f16x2*)(zr + jh);
    f16x2 vf = *(const f16x2*)(zr + H_ + jh);
    f16x2 vg = *(const f16x2*)(zr + 2 * H_ + jh);
    f16x2 vo = *(const f16x2*)(zr + 3 * H_ + jh);

    float nhv[2], ncv[2];
    #pragma unroll
    for (int u = 0; u < 2; u++) {
        int j = jh + u;
        float zi = (float)vi[u] + bias[j];
        float zf = (float)vf[u] + bias[H_ + j];
        float zg = (float)vg[u] + bias[2 * H_ + j];
        float zo = (float)vo[u] + bias[3 * H_ + j];
        float cp = 0.f;
        if (useinit) {
            const float* hzr = hz0 + (size_t)b * 2048;
            zi += hzr[j]; zf += hzr[H_ + j]; zg += hzr[2 * H_ + j]; zo += hzr[3 * H_ + j];
            cp = c0[b * H_ + j];
        }
        float iv = sigm(zi), fv = sigm(zf), gv = tanha(zg), ov = sigm(zo);
        float nc = fv * cp + iv * gv;
        float nh = ov * tanha(nc);
        ncv[u] = fminf(1.f, fmaxf(-1.f, nc));
        nhv[u] = fminf(1.f, fmaxf(-1.f, nh));
        ys[(size_t)tb * H_ + j] = nhv[u];
    }
    if (s >= 0) {
        f16x2 hv, cv;
        hv[0] = (f16)nhv[0]; hv[1] = (f16)nhv[1];
        cv[0] = (f16)ncv[0]; cv[1] = (f16)ncv[1];
        *(f16x2*)(Hb + (size_t)s * H_ + jh) = hv;
        *(f16x2*)(Cb + (size_t)s * H_ + jh) = cv;
    }
}

// A5: level k>=1: h-GEMM (K=512) + epilogue adding XZ + bias.
// Tile: 64 rows x 64 hidden (=256 z-cols, 4 gates), padded LDS, 4 waves.
__global__ __launch_bounds__(256) void k_levelh(
    int level,
    const int* __restrict__ resets,
    const f16* __restrict__ W2t,
    const float* __restrict__ bias,
    const f16* __restrict__ XZ,
    f16* __restrict__ Hb,
    f16* __restrict__ Cb,
    const int* __restrict__ meta,
    const int* __restrict__ rmap,
    const int* __restrict__ rowid,
    float* __restrict__ ys)
{
    const int cnt = meta[M_CNT + level];
    const int row0 = blockIdx.x * 64;
    if (row0 >= cnt) return;
    const int off = meta[M_OFF + level];
    const int j0 = blockIdx.y * 64;

    __shared__ __align__(16) f16 As[64][40];
    __shared__ __align__(16) f16 Ws[256][40];

    const int tid  = threadIdx.x;
    const int lane = tid & 63;
    const int wave = tid >> 6;
    const int n = lane & 15;
    const int q = lane >> 4;

    fx4 acc[16];
    #pragma unroll
    for (int i = 0; i < 16; i++) acc[i] = (fx4){0.f, 0.f, 0.f, 0.f};

    const int ar  = tid >> 2;
    const int ach = tid & 3;
    const int gr_stage = row0 + ar;
    const int srow = off + (gr_stage < cnt ? gr_stage : 0);
    const f16* agp = Hb + (size_t)srow * H_ + ach * 8;
    const int wc = tid >> 2;

    for (int k0 = 0; k0 < 512; k0 += 32) {
        *(uint4*)(&As[ar][ach * 8]) = *(const uint4*)(agp + k0);
        #pragma unroll
        for (int s = 0; s < 4; s++) {
            const f16* wp = W2t + (size_t)(s * H_ + j0 + wc) * 1024 + 512 + k0 + ach * 8;
            *(uint4*)(&Ws[s * 64 + wc][ach * 8]) = *(const uint4*)wp;
        }
        __syncthreads();
        f16x8 a = *(const f16x8*)(&As[wave * 16 + n][q * 8]);
        #pragma unroll
        for (int ct = 0; ct < 16; ct++) {
            f16x8 bb = *(const f16x8*)(&Ws[ct * 16 + n][q * 8]);
            acc[ct] = __builtin_amdgcn_mfma_f32_16x16x32_f16(a, bb, acc[ct], 0, 0, 0);
        }
        __syncthreads();
    }

    int tbs[4], succs[4], grows[4], valids[4];
    #pragma unroll
    for (int reg = 0; reg < 4; reg++) {
        int gr = row0 + wave * 16 + q * 4 + reg;
        valids[reg] = (gr < cnt);
        int grow = off + (gr < cnt ? gr : 0);
        grows[reg] = grow;
        int tb = rmap[grow];
        tbs[reg] = tb;
        int s = -1;
        if (gr < cnt && (tb >> 6) + 1 < T_ && resets[tb + B_] == 0) s = rowid[tb + B_];
        succs[reg] = s;
    }
    #pragma unroll
    for (int jt = 0; jt < 4; jt++) {
        int j = j0 + jt * 16 + n;
        float b_i = bias[j], b_f = bias[H_ + j], b_g = bias[2 * H_ + j], b_o = bias[3 * H_ + j];
        #pragma unroll
        for (int reg = 0; reg < 4; reg++) {
            if (!valids[reg]) continue;
            const f16* zr = XZ + (size_t)tbs[reg] * 2048;
            float zi = acc[jt][reg]      + b_i + (float)zr[j];
            float zf = acc[4 + jt][reg]  + b_f + (float)zr[H_ + j];
            float zg = acc[8 + jt][reg]  + b_g + (float)zr[2 * H_ + j];
            float zo = acc[12 + jt][reg] + b_o + (float)zr[3 * H_ + j];
            float cp = (float)Cb[(size_t)grows[reg] * H_ + j];
            float iv = sigm(zi), fv = sigm(zf), gv = tanha(zg), ov = sigm(zo);
            float nc = fv * cp + iv * gv;
            float nh = ov * tanha(nc);
            float ncc = fminf(1.f, fmaxf(-1.f, nc));
            float nhc = fminf(1.f, fmaxf(-1.f, nh));
            ys[(size_t)tbs[reg] * H_ + j] = nhc;
            int s = succs[reg];
            if (s >= 0) {
                Hb[(size_t)s * H_ + j] = (f16)nhc;
                Cb[(size_t)s * H_ + j] = (f16)ncc;
            }
        }
    }
}

// ===========================================================================
// PATH B kernels (fallback, r2 structure + LDS padding)
// ===========================================================================

__global__ __launch_bounds__(256) void k_fill(const float* __restrict__ xs,
                                              const float* __restrict__ c0,
                                              const float* __restrict__ h0,
                                              const int* __restrict__ resets,
                                              const int* __restrict__ rmap,
                                              const int* __restrict__ meta,
                                              f16* __restrict__ A,
                                              f16* __restrict__ Cb) {
    int gid = blockIdx.x * 256 + threadIdx.x;
    int r = gid >> 6, seg = gid & 63;
    int tb = rmap[r];
    const float4* src = (const float4*)(xs + (size_t)tb * H_ + seg * 8);
    float4 a = src[0];
    float4 c = src[1];
    f16x8 o;
    o[0]=(f16)a.x; o[1]=(f16)a.y; o[2]=(f16)a.z; o[3]=(f16)a.w;
    o[4]=(f16)c.x; o[5]=(f16)c.y; o[6]=(f16)c.z; o[7]=(f16)c.w;
    *(f16x8*)(A + (size_t)r * 1024 + seg * 8) = o;

    if (r < meta[M_CNT + 0]) {
        int t = tb >> 6, b = tb & 63;
        bool useinit = (t == 0) && (resets[b] == 0);
        f16x8 hv, cv;
        #pragma unroll
        for (int u = 0; u < 8; u++) {
            int j = seg * 8 + u;
            hv[u] = (f16)(useinit ? h0[b * H_ + j] : 0.0f);
            cv[u] = (f16)(useinit ? c0[b * H_ + j] : 0.0f);
        }
        *(f16x8*)(A + (size_t)r * 1024 + H_ + seg * 8) = hv;
        *(f16x8*)(Cb + (size_t)r * H_ + seg * 8) = cv;
    }
}

__global__ __launch_bounds__(256) void k_level(
    int level,
    const int* __restrict__ resets,
    const f16* __restrict__ W2t,
    const float* __restrict__ bias,
    f16* __restrict__ Ab,
    f16* __restrict__ Cb,
    const int* __restrict__ meta,
    const int* __restrict__ rmap,
    const int* __restrict__ rowid,
    float* __restrict__ ys)
{
    const int cnt = meta[M_CNT + level];
    const int row0 = blockIdx.x * 64;
    if (row0 >= cnt) return;
    const int off = meta[M_OFF + level];
    const int j0 = blockIdx.y * 64;

    __shared__ __align__(16) f16 As[64][40];
    __shared__ __align__(16) f16 Ws[256][40];

    const int tid  = threadIdx.x;
    const int lane = tid & 63;
    const int wave = tid >> 6;
    const int n = lane & 15;
    const int q = lane >> 4;

    fx4 acc[16];
    #pragma unroll
    for (int i = 0; i < 16; i++) acc[i] = (fx4){0.f, 0.f, 0.f, 0.f};

    const int ar  = tid >> 2;
    const int ach = tid & 3;
    const int gr_stage = row0 + ar;
    const int srow = off + (gr_stage < cnt ? gr_stage : 0);
    const f16* agp = Ab + (size_t)srow * 1024 + ach * 8;
    const int wc = tid >> 2;

    for (int k0 = 0; k0 < 1024; k0 += 32) {
        *(uint4*)(&As[ar][ach * 8]) = *(const uint4*)(agp + k0);
        #pragma unroll
        for (int s = 0; s < 4; s++) {
            const f16* wp = W2t + (size_t)(s * H_ + j0 + wc) * 1024 + k0 + ach * 8;
            *(uint4*)(&Ws[s * 64 + wc][ach * 8]) = *(const uint4*)wp;
        }
        __syncthreads();
        f16x8 a = *(const f16x8*)(&As[wave * 16 + n][q * 8]);
        #pragma unroll
        for (int ct = 0; ct < 16; ct++) {
            f16x8 bb = *(const f16x8*)(&Ws[ct * 16 + n][q * 8]);
            acc[ct] = __builtin_amdgcn_mfma_f32_16x16x32_f16(a, bb, acc[ct], 0, 0, 0);
        }
        __syncthreads();
    }

    int tbs[4], succs[4], grows[4], valids[4];
    #pragma unroll
    for (int reg = 0; reg < 4; reg++) {
        int gr = row0 + wave * 16 + q * 4 + reg;
        valids[reg] = (gr < cnt);
        int grow = off + (gr < cnt ? gr : 0);
        grows[reg] = grow;
        int tb = rmap[grow];
        tbs[reg] = tb;
        int s = -1;
        if (gr < cnt && (tb >> 6) + 1 < T_ && resets[tb + B_] == 0) s = rowid[tb + B_];
        succs[reg] = s;
    }
    #pragma unroll
    for (int jt = 0; jt < 4; jt++) {
        int j = j0 + jt * 16 + n;
        float b_i = bias[j], b_f = bias[H_ + j], b_g = bias[2 * H_ + j], b_o = bias[3 * H_ + j];
        #pragma unroll
        for (int reg = 0; reg < 4; reg++) {
            if (!valids[reg]) continue;
            float zi = acc[jt][reg] + b_i;
            float zf = acc[4 + jt][reg] + b_f;
            float zg = acc[8 + jt][reg] + b_g;
            float zo = acc[12 + jt][reg] + b_o;
            float cp = (float)Cb[(size_t)grows[reg] * H_ + j];
            float iv = sigm(zi), fv = sigm(zf), gv = tanha(zg), ov = sigm(zo);
            float nc = fv * cp + iv * gv;
            float nh = ov * tanha(nc);
            float ncc = fminf(1.f, fmaxf(-1.f, nc));
            float nhc = fminf(1.f, fmaxf(-1.f, nh));
            ys[(size_t)tbs[reg] * H_ + j] = nhc;
            int s = succs[reg];
            if (s >= 0) {
                Ab[(size_t)s * 1024 + H_ + j] = (f16)nhc;
                Cb[(size_t)s * H_ + j] = (f16)ncc;
            }
        }
    }
}

// ---------------------------------------------------------------------------
// Shared: fp32 cleanup for rows at level >= LMAX, bucket-driven (no lvl scan)
// ---------------------------------------------------------------------------
__global__ __launch_bounds__(256) void k_cleanup(
    const float* __restrict__ xs, const float* __restrict__ Wi,
    const float* __restrict__ Wh, const float* __restrict__ bias,
    const int* __restrict__ rowid, const int* __restrict__ meta,
    const int* __restrict__ rmap,
    const f16* __restrict__ Cb, float* __restrict__ ys)
{
    const int cntL = meta[M_CNT + LMAX];
    if (cntL == 0) return;
    const int offL = meta[M_OFF + LMAX];
    const int b = blockIdx.x;
    const int tid = threadIdx.x;
    __shared__ float hs[H_], cs[H_];
    int last_t = -2;
    for (int idx = 0; idx < cntL; idx++) {
        const int tb = rmap[offL + idx];
        if ((tb & 63) != b) continue;
        const int t = tb >> 6;
        if (t != last_t + 1) {
            for (int j = tid; j < H_; j += 256) {
                hs[j] = ys[(size_t)(tb - B_) * H_ + j];
                cs[j] = (float)Cb[(size_t)rowid[tb] * H_ + j];
            }
        }
        __syncthreads();
        float nh_[2], nc_[2];
        #pragma unroll
        for (int u = 0; u < 2; u++) {
            int j = tid + u * 256;
            float zi = bias[j], zf = bias[H_ + j], zg = bias[2 * H_ + j], zo = bias[3 * H_ + j];
            const float* xr = xs + (size_t)tb * H_;
            for (int k = 0; k < H_; k++) {
                float xk = xr[k], hk = hs[k];
                zi += xk * Wi[(size_t)k * 2048 + j]          + hk * Wh[(size_t)k * 2048 + j];
                zf += xk * Wi[(size_t)k * 2048 + H_ + j]     + hk * Wh[(size_t)k * 2048 + H_ + j];
                zg += xk * Wi[(size_t)k * 2048 + 2 * H_ + j] + hk * Wh[(size_t)k * 2048 + 2 * H_ + j];
                zo += xk * Wi[(size_t)k * 2048 + 3 * H_ + j] + hk * Wh[(size_t)k * 2048 + 3 * H_ + j];
            }
            float cp = cs[j];
            float iv = sigm(zi), fv = sigm(zf), gv = tanha(zg), ov = sigm(zo);
            float nc = fv * cp + iv * gv;
            float nh = ov * tanha(nc);
            nc_[u] = fminf(1.f, fmaxf(-1.f, nc));
            nh_[u] = fminf(1.f, fmaxf(-1.f, nh));
            ys[(size_t)tb * H_ + j] = nh_[u];
        }
        __syncthreads();
        #pragma unroll
        for (int u = 0; u < 2; u++) { int j = tid + u * 256; hs[j] = nh_[u]; cs[j] = nc_[u]; }
        last_t = t;
    }
}

// ---------------------------------------------------------------------------
// PATH C: last-resort sequential fallback
// ---------------------------------------------------------------------------
__global__ __launch_bounds__(256) void k_fb_init(const float* __restrict__ c0,
                                                 const float* __restrict__ h0,
                                                 float* __restrict__ cbuf,
                                                 float* __restrict__ hA) {
    int idx = blockIdx.x * 256 + threadIdx.x;
    if (idx >= B_ * H_) return;
    cbuf[idx] = c0[idx];
    hA[idx] = h0[idx];
}

__global__ __launch_bounds__(256) void k_fb_step(
    int t,
    const float* __restrict__ xs, const int* __restrict__ resets,
    const float* __restrict__ Wi, const float* __restrict__ Wh,
    const float* __restrict__ bias,
    const float* __restrict__ hin, float* __restrict__ hout,
    float* __restrict__ cbuf, float* __restrict__ ys)
{
    int idx = blockIdx.x * 256 + threadIdx.x;
    int b = idx >> 9, j = idx & 511;
    int tb = t * B_ + b;
    bool rst = resets[tb] != 0;
    float zi = bias[j], zf = bias[H_ + j], zg = bias[2 * H_ + j], zo = bias[3 * H_ + j];
    const float* xr = xs + (size_t)tb * H_;
    for (int k = 0; k < H_; k++) {
        float xk = xr[k];
        zi += xk * Wi[(size_t)k * 2048 + j];
        zf += xk * Wi[(size_t)k * 2048 + H_ + j];
        zg += xk * Wi[(size_t)k * 2048 + 2 * H_ + j];
        zo += xk * Wi[(size_t)k * 2048 + 3 * H_ + j];
    }
    if (!rst) {
        const float* hr = hin + b * H_;
        for (int k = 0; k < H_; k++) {
            float hk = hr[k];
            zi += hk * Wh[(size_t)k * 2048 + j];
            zf += hk * Wh[(size_t)k * 2048 + H_ + j];
            zg += hk * Wh[(size_t)k * 2048 + 2 * H_ + j];
            zo += hk * Wh[(size_t)k * 2048 + 3 * H_ + j];
        }
    }
    float cp = rst ? 0.f : cbuf[idx];
    float iv = sigm(zi), fv = sigm(zf), gv = tanha(zg), ov = sigm(zo);
    float nc = fv * cp + iv * gv;
    float nh = ov * tanha(nc);
    float ncc = fminf(1.f, fmaxf(-1.f, nc));
    float nhc = fminf(1.f, fmaxf(-1.f, nh));
    cbuf[idx] = ncc;
    hout[idx] = nhc;
    ys[(size_t)tb * H_ + j] = nhc;
}

// ---------------------------------------------------------------------------
extern "C" void kernel_launch(void* const* d_in, const int* in_sizes, int n_in,
                              void* d_out, int out_size, void* d_ws, size_t ws_size,
                              hipStream_t stream) {
    const float* xs    = (const float*)d_in[0];
    const int*   resets= (const int*)d_in[1];
    const float* c0    = (const float*)d_in[2];
    const float* h0    = (const float*)d_in[3];
    const float* Wi    = (const float*)d_in[4];
    const float* Wh    = (const float*)d_in[5];
    const float* bias  = (const float*)d_in[6];
    float* ys = (float*)d_out;
    char* ws = (char*)d_ws;

    // ---- Path A layout ----
    const size_t A_W2T  = 0;                          // 4 MiB
    const size_t A_X    = A_W2T + (size_t)4*1024*1024;        // 32 MiB
    const size_t A_XZ   = A_X   + (size_t)32*1024*1024;       // 128 MiB
    const size_t A_HB   = A_XZ  + (size_t)128*1024*1024;      // 32 MiB
    const size_t A_CB   = A_HB  + (size_t)32*1024*1024;       // 32 MiB
    const size_t A_HZ0  = A_CB  + (size_t)32*1024*1024;       // 512 KiB
    const size_t A_LVL  = A_HZ0 + (size_t)512*1024;
    const size_t A_RID  = A_LVL + 131072;
    const size_t A_RMAP = A_RID + 131072;
    const size_t A_META = A_RMAP + 131072;
    const size_t NEEDED_A = A_META + 512;

    // ---- Path B layout ----
    const size_t B_A    = 0;
    const size_t B_C    = 67108864;
    const size_t B_W2T  = 100663296;
    const size_t B_LVL  = 104857600;
    const size_t B_RID  = 104988672;
    const size_t B_RMAP = 105119744;
    const size_t B_META = 105250816;
    const size_t NEEDED_B = 105251328;

    if (ws_size >= NEEDED_A) {
        f16* W2t  = (f16*)(ws + A_W2T);
        f16* X    = (f16*)(ws + A_X);
        f16* XZ   = (f16*)(ws + A_XZ);
        f16* Hb   = (f16*)(ws + A_HB);
        f16* Cb   = (f16*)(ws + A_CB);
        float* hz0= (float*)(ws + A_HZ0);
        int* lvl  = (int*)(ws + A_LVL);
        int* rid  = (int*)(ws + A_RID);
        int* rmap = (int*)(ws + A_RMAP);
        int* meta = (int*)(ws + A_META);

        k_prepw<<<dim3(32, 16), dim3(256), 0, stream>>>(Wi, Wh, W2t);
        k_scan_build<<<dim3(1), dim3(256), 0, stream>>>(resets, lvl, meta, rid, rmap);
        k_xcast<<<dim3(NROWS * 64 / 256 / 8 * 8), dim3(256), 0, stream>>>(xs, X);
        k_hz0<<<dim3(512), dim3(256), 0, stream>>>(h0, W2t, hz0);
        k_xz<<<dim3(NROWS / 128, 16), dim3(256), 0, stream>>>(X, W2t, XZ);
        k_lvl0epi<<<dim3(NROWS), dim3(256), 0, stream>>>(XZ, hz0, c0, bias, resets,
                                                         meta, rmap, rid, Hb, Cb, ys);
        for (int k = 1; k < LMAX; k++) {
            int maxr = 64 * ((512 + k) / (k + 1));
            dim3 grid((maxr + 63) / 64, 8);
            k_levelh<<<grid, dim3(256), 0, stream>>>(k, resets, W2t, bias, XZ, Hb, Cb,
                                                     meta, rmap, rid, ys);
        }
        k_cleanup<<<dim3(64), dim3(256), 0, stream>>>(xs, Wi, Wh, bias, rid, meta, rmap, Cb, ys);
    } else if (ws_size >= NEEDED_B) {
        f16* A    = (f16*)(ws + B_A);
        f16* Cb   = (f16*)(ws + B_C);
        f16* W2t  = (f16*)(ws + B_W2T);
        int* lvl  = (int*)(ws + B_LVL);
        int* rid  = (int*)(ws + B_RID);
        int* rmap = (int*)(ws + B_RMAP);
        int* meta = (int*)(ws + B_META);

        k_prepw<<<dim3(32, 16), dim3(256), 0, stream>>>(Wi, Wh, W2t);
        k_scan_build<<<dim3(1), dim3(256), 0, stream>>>(resets, lvl, meta, rid, rmap);
        k_fill<<<dim3(NROWS * 64 / 256), dim3(256), 0, stream>>>(xs, c0, h0, resets, rmap, meta, A, Cb);
        for (int k = 0; k < LMAX; k++) {
            int maxr = 64 * ((512 + k) / (k + 1));
            dim3 grid((maxr + 63) / 64, 8);
            k_level<<<grid, dim3(256), 0, stream>>>(k, resets, W2t, bias, A, Cb,
                                                    meta, rmap, rid, ys);
        }
        k_cleanup<<<dim3(64), dim3(256), 0, stream>>>(xs, Wi, Wh, bias, rid, meta, rmap, Cb, ys);
    } else {
        float* cbuf = (float*)(ws);
        float* hA   = (float*)(ws + 131072);
        float* hB   = (float*)(ws + 262144);
        k_fb_init<<<dim3(128), dim3(256), 0, stream>>>(c0, h0, cbuf, hA);
        for (int t = 0; t < T_; t++) {
            const float* hin = (t & 1) ? hB : hA;
            float* hout      = (t & 1) ? hA : hB;
            k_fb_step<<<dim3(128), dim3(256), 0, stream>>>(t, xs, resets, Wi, Wh, bias,
                                                           hin, hout, cbuf, ys);
        }
    }
}